// Round 1
// 720.122 us; speedup vs baseline: 1.1542x; 1.1542x over previous
//
#include <hip/hip_runtime.h>
#include <math.h>

// ---------- Problem constants ----------
#define N_NODES 65536
#define B_GR    8
#define EMB_N   512
#define E_EDGES 458752     // N * 7
#define NSEG    458752     // N * 7 segments (row*7 + etype)
#define TSTRIDE 288        // per-type padded K (263 used: 256 feat + 7 onehot)
#define GK      2016       // 7 * 288, multiple of 32
#define EPS     1e-5f

typedef unsigned short u16;
typedef unsigned int   u32;
typedef __bf16 bf16x8 __attribute__((ext_vector_type(8)));
typedef float  f32x4  __attribute__((ext_vector_type(4)));
typedef u16    u16x8  __attribute__((ext_vector_type(8)));

__device__ __forceinline__ float bf2f(u16 u) {
    u32 x = ((u32)u) << 16; float f; __builtin_memcpy(&f, &x, 4); return f;
}
__device__ __forceinline__ u16 f2bf(float f) {
    u32 x; __builtin_memcpy(&x, &f, 4);
    u32 r = x + 0x7fffu + ((x >> 16) & 1u);
    return (u16)(r >> 16);
}

// XOR swizzle: k-slot 'k8' of row 'row' lives at slot k8 ^ ((row>>1)&3).
// Frag reads (16 consecutive rows, fixed lq) hit 8 distinct bank-starts
// x 2 lanes = 2-way (free, m136); writes stay a permutation per row.
#define SW(row, k8) ((k8) ^ (((row) >> 1) & 3))

// ---------- zero scratch (hist + S + Q + cnt) ----------
__global__ __launch_bounds__(256) void zero_kernel(int* __restrict__ hist,
                                                   float* __restrict__ S, float* __restrict__ Q,
                                                   int* __restrict__ cnt) {
    int i = blockIdx.x * 256 + threadIdx.x;
    if (i < NSEG) hist[i] = 0;
    if (i < 2048) { S[i] = 0.f; Q[i] = 0.f; }
    if (i < 8) cnt[i] = 0;
}

// ---------- per-batch node counts (once; batch_id sorted, wave-ballot) ----------
__global__ __launch_bounds__(256) void count_kernel(const int* __restrict__ batch_id,
                                                    int* __restrict__ cnt) {
    int i = blockIdx.x * 256 + threadIdx.x;
    int b = batch_id[i];
#pragma unroll
    for (int bb = 0; bb < 8; bb++) {
        unsigned long long m = __ballot(b == bb);
        if ((threadIdx.x & 63) == 0 && m)
            atomicAdd(&cnt[bb], (int)__popcll(m));
    }
}

// ---------- weight transpose+pad (f32 -> bf16, LDS-tiled coalesced)  and  emb GEMM ----------
// Wt[n][t*288+c] = bf16(W[(t*263+c)*256 + n])  (c<263, else 0)
// 32(c) x 32(n) tiles: reads coalesced along n, writes coalesced along c.
__global__ __launch_bounds__(256) void prep_kernel(
    const float* __restrict__ w1, const float* __restrict__ w2,
    u16* __restrict__ Wt1, u16* __restrict__ Wt2,
    const float* __restrict__ emb, const float* __restrict__ embw,
    const float* __restrict__ embb, float* __restrict__ embout)
{
    int bid = blockIdx.x, tid = threadIdx.x;
    if (bid < 1008) {
        const float* Win = (bid < 504) ? w1 : w2;
        u16* Wt = (bid < 504) ? Wt1 : Wt2;
        int r  = bid % 504;
        int t  = r / 72;               // 0..6
        int r2 = r % 72;
        int c0 = (r2 / 8) * 32;        // 9 c-tiles cover padded 0..287
        int n0 = (r2 % 8) * 32;
        __shared__ float tile[32][33];
        int cl = tid & 31, rh = tid >> 5;   // rh 0..7
#pragma unroll
        for (int rr = 0; rr < 4; rr++) {
            int c = c0 + rh + rr * 8;
            float v = 0.f;
            if (c < 263) v = Win[(size_t)(t * 263 + c) * 256 + n0 + cl];
            tile[rh + rr * 8][cl] = v;
        }
        __syncthreads();
#pragma unroll
        for (int rr = 0; rr < 4; rr++) {
            int n = n0 + rh + rr * 8;
            Wt[(size_t)n * GK + t * TSTRIDE + c0 + cl] = f2bf(tile[cl][rh + rr * 8]);
        }
    } else {
        __shared__ float semb[B_GR * EMB_N];
        for (int i = tid; i < B_GR * EMB_N; i += 256) {
            float e = emb[i];
            semb[i] = e / (1.f + expf(-e));
        }
        __syncthreads();
        float acc[8];
        float bb = embb[tid];
#pragma unroll
        for (int b = 0; b < 8; b++) acc[b] = bb;
        for (int k = 0; k < EMB_N; k++) {
            float wv = embw[k * 256 + tid];
#pragma unroll
            for (int b = 0; b < 8; b++) acc[b] += semb[b * EMB_N + k] * wv;
        }
#pragma unroll
        for (int b = 0; b < 8; b++) embout[b * 256 + tid] = acc[b];
    }
}

// ---------- group-norm stats: per (batch, channel) sums ----------
__global__ __launch_bounds__(256) void stats_kernel(const float* __restrict__ xin,
                                                    const int* __restrict__ batch_id,
                                                    float* __restrict__ S, float* __restrict__ Q) {
    int c = threadIdx.x;
    int n0 = blockIdx.x * 64;
    float s = 0.f, q = 0.f;
    int bcur = batch_id[n0];
    for (int r = 0; r < 64; r++) {
        int n = n0 + r;
        int b = batch_id[n];
        if (b != bcur) {
            atomicAdd(&S[bcur * 256 + c], s);
            atomicAdd(&Q[bcur * 256 + c], q);
            s = 0.f; q = 0.f; bcur = b;
        }
        float v = xin[(size_t)n * 256 + c];
        s += v;
        q = fmaf(v, v, q);
    }
    atomicAdd(&S[bcur * 256 + c], s);
    atomicAdd(&Q[bcur * 256 + c], q);
}

// ---------- finalize: per-(b,group) mean / inv_std; zeroes S/Q for next round ----------
__global__ __launch_bounds__(256) void finalize_kernel(const int* __restrict__ cnt,
                                                       float* __restrict__ S, float* __restrict__ Q,
                                                       float* __restrict__ gmean, float* __restrict__ gistd) {
    int tid = threadIdx.x;
    int b = tid >> 5, g = tid & 31;
    float Sg = 0.f, Qg = 0.f;
#pragma unroll
    for (int k = 0; k < 8; k++) {
        int idx = b * 256 + g * 8 + k;
        Sg += S[idx];
        Qg += Q[idx];
        S[idx] = 0.f;
        Q[idx] = 0.f;
    }
    float cnt8 = (float)cnt[b] * 8.f;
    float D = cnt8 + EPS;                      // matches reference: count*cpg + EPS
    float m = Sg / D;
    float var = (Qg - 2.f * m * Sg + cnt8 * m * m) / D;
    float istd = rsqrtf(var + EPS);
    gmean[tid] = m;      // tid = b*32+g
    gistd[tid] = istd;
}

// ---------- normalize + affine + SiLU: f32 in -> bf16 y ----------
__global__ __launch_bounds__(256) void norm_silu_kernel(const float* __restrict__ xin,
                                                        const int* __restrict__ batch_id,
                                                        const float* __restrict__ gmean, const float* __restrict__ gistd,
                                                        const float* __restrict__ w, const float* __restrict__ bias,
                                                        u16* __restrict__ yout) {
    int tid = threadIdx.x;
    int n = blockIdx.x * 8 + (tid >> 5);
    int g = tid & 31;
    int c0 = g * 8;
    int b = batch_id[n];
    float m = gmean[b * 32 + g], is = gistd[b * 32 + g];
    u16x8 o;
#pragma unroll
    for (int k = 0; k < 8; k++) {
        float v = (xin[(size_t)n * 256 + c0 + k] - m) * is;
        v = v * w[c0 + k] + bias[c0 + k];
        v = v / (1.f + expf(-v));
        o[k] = f2bf(v);
    }
    *(u16x8*)&yout[(size_t)n * 256 + c0] = o;
}

// ---------- CSR build ----------
__global__ __launch_bounds__(256) void hist_kernel(const int* __restrict__ ei, const int* __restrict__ et,
                                                   int* __restrict__ hist) {
    int e = blockIdx.x * 256 + threadIdx.x;
    if (e >= E_EDGES) return;
    int s = ei[e] * 7 + et[e];
    atomicAdd(&hist[s], 1);
}

__global__ __launch_bounds__(512) void scan1_kernel(const int* __restrict__ hist, int* __restrict__ partials) {
    __shared__ int sd[512];
    int i = blockIdx.x * 512 + threadIdx.x;
    sd[threadIdx.x] = hist[i];
    __syncthreads();
    for (int off = 256; off > 0; off >>= 1) {
        if (threadIdx.x < off) sd[threadIdx.x] += sd[threadIdx.x + off];
        __syncthreads();
    }
    if (threadIdx.x == 0) partials[blockIdx.x] = sd[0];
}

__global__ __launch_bounds__(1024) void scan2_kernel(int* __restrict__ partials) {
    __shared__ int sd[1024];
    int t = threadIdx.x;
    int v = (t < 896) ? partials[t] : 0;
    sd[t] = v;
    __syncthreads();
    for (int off = 1; off < 1024; off <<= 1) {
        int u = (t >= off) ? sd[t - off] : 0;
        __syncthreads();
        sd[t] += u;
        __syncthreads();
    }
    if (t < 896) partials[t] = sd[t] - v;   // exclusive
}

// In-place: reads hist[i], writes offsets over the same buffer.
__global__ __launch_bounds__(512) void scan3_kernel(int* __restrict__ hist_offs, const int* __restrict__ partials,
                                                    int* __restrict__ cursor) {
    __shared__ int sd[512];
    int t = threadIdx.x;
    int i = blockIdx.x * 512 + t;
    int c = hist_offs[i];
    sd[t] = c;
    __syncthreads();
    for (int off = 1; off < 512; off <<= 1) {
        int u = (t >= off) ? sd[t - off] : 0;
        __syncthreads();
        sd[t] += u;
        __syncthreads();
    }
    int o = partials[blockIdx.x] + sd[t] - c;
    hist_offs[i] = o;
    cursor[i] = o;
}

__global__ __launch_bounds__(256) void fill_kernel(const int* __restrict__ ei, const int* __restrict__ et,
                                                   int* __restrict__ cursor, int* __restrict__ elist) {
    int e = blockIdx.x * 256 + threadIdx.x;
    if (e >= E_EDGES) return;
    int s = ei[e] * 7 + et[e];
    int p = atomicAdd(&cursor[s], 1);
    if (p >= 0 && p < E_EDGES) elist[p] = ei[E_EDGES + e];   // col
}

// ---------- fused aggregate + MFMA GEMM (BM=64, BN=256, 512 thr, 8 waves) ----------
// Per-wave tile 64(m) x 32(n): acc = 4x2 f32x4 = 32 regs (was 64) so with
// __launch_bounds__(512,4) the unified VGPR file fits 4 waves/SIMD (16/CU),
// double the previous 2-wave cap (VGPR 104 + 64 AGPR = 168 -> 2 waves).
// B is read DIRECTLY from L2-resident Wt into a ping-pong register pair
// (no Bs LDS, no second barrier). As is double-buffered -> ONE barrier/chunk.
// A-build: 2 threads per (row,quarter) slot split the edge list by parity;
// partial sums combined with one __shfl_xor per channel; half==0 writes LDS.
// CSR state for type t+1 is pipelined: offs/cursor at c9==6, elist at c9==7,
// chunk-0 gather at c9==8 -- no serial 3-deep load chain at type boundaries.
// ALL y-gathers index y with the FULL offset col*256 + chunk*32 + aq*8
// (round 7 bug: a pre-offset yq base double-counted aq*8).
// mode 0: out = acc + embout[batch_id[m]][n]   (h2 f32, in d_out)
// mode 1: out = acc + x[m][n]                  (final f32 output)
__global__ __launch_bounds__(512, 4) void gemm_fused_kernel(
    const u16* __restrict__ y, const u16* __restrict__ Bt,
    const int* __restrict__ offs, const int* __restrict__ cursor,
    const int* __restrict__ elist, const int* __restrict__ node_type,
    const int* __restrict__ batch_id, const float* __restrict__ embout,
    const float* __restrict__ xres, float* __restrict__ out, int mode)
{
    __shared__ __align__(16) u16 As[2][64 * 32];   // 8 KB double-buffered
    int tid = threadIdx.x;
    int lane = tid & 63;
    int wn = tid >> 6;                 // 8 waves, each 64(m) x 32(n)
    int lm = lane & 15, lq = lane >> 4;
    int m0 = blockIdx.x * 64;
    int ar = tid >> 3;                 // A-build row 0..63
    int aq = (tid >> 1) & 3;           // 8-channel quarter
    int half = tid & 1;                // edge-parity split within the slot

    f32x4 acc[4][2];
    f32x4 zz = {0.f, 0.f, 0.f, 0.f};
#pragma unroll
    for (int i = 0; i < 4; i++)
#pragma unroll
        for (int j = 0; j < 2; j++) acc[i][j] = zz;

    const u16* btp0 = Bt + (size_t)(wn * 32 + lm) * GK + lq * 8;
    const u16* btp1 = btp0 + (size_t)16 * GK;

    // ---- type-0 CSR + chunk-0 gather (unpipelined prologue) ----
    int sbase = (m0 + ar) * 7;
    int st = offs[sbase], en = cursor[sbase];
    int col[2];
    col[0] = (st + half     < en) ? elist[st + half]     : -1;
    col[1] = (st + half + 2 < en) ? elist[st + half + 2] : -1;

    float a8[8];
#pragma unroll
    for (int j = 0; j < 8; j++) a8[j] = 0.f;
#pragma unroll
    for (int u = 0; u < 2; u++)
        if (col[u] >= 0) {
            u16x8 v = *(const u16x8*)&y[(size_t)col[u] * 256 + aq * 8];
#pragma unroll
            for (int j = 0; j < 8; j++) a8[j] += bf2f(v[j]);
        }
    if (en - st > 4)
        for (int e = st + 4 + half; e < en; e += 2) {
            u16x8 v = *(const u16x8*)&y[(size_t)elist[e] * 256 + aq * 8];
#pragma unroll
            for (int j = 0; j < 8; j++) a8[j] += bf2f(v[j]);
        }

    bf16x8 bcur[2], bnxt[2];
    bcur[0] = *(const bf16x8*)&btp0[0];
    bcur[1] = *(const bf16x8*)&btp1[0];

    int st_n = 0, en_n = 0;
    int coln[2] = {-1, -1};
    int buf = 0;

    for (int t = 0; t < 7; t++) {
#pragma unroll
        for (int c9 = 0; c9 < 9; c9++) {
            // ---- combine halves, write As[buf] ----
#pragma unroll
            for (int j = 0; j < 8; j++) a8[j] += __shfl_xor(a8[j], 1);
            if (half == 0) {
                u16x8 o;
#pragma unroll
                for (int j = 0; j < 8; j++) o[j] = f2bf(a8[j]);
                *(u16x8*)&As[buf][ar * 32 + SW(ar, aq) * 8] = o;
            }
            __syncthreads();
            // ---- A fragments ----
            bf16x8 a[4];
#pragma unroll
            for (int i = 0; i < 4; i++) {
                int ra = i * 16 + lm;
                a[i] = *(const bf16x8*)&As[buf][ra * 32 + SW(ra, lq) * 8];
            }
            // ---- prefetch next chunk (registers only; overlaps MFMA) ----
            u16x8 gv[2];
            int nt2[2];
#pragma unroll
            for (int j = 0; j < 8; j++) a8[j] = 0.f;
            if (c9 < 7) {
                int cb = (c9 + 1) * 32 + aq * 8;
#pragma unroll
                for (int u = 0; u < 2; u++)
                    if (col[u] >= 0) gv[u] = *(const u16x8*)&y[(size_t)col[u] * 256 + cb];
                int kb = t * TSTRIDE + (c9 + 1) * 32;
                bnxt[0] = *(const bf16x8*)&btp0[kb];
                bnxt[1] = *(const bf16x8*)&btp1[kb];
                if (c9 == 6 && t < 6) {
                    int sn = sbase + t + 1;
                    st_n = offs[sn];
                    en_n = cursor[sn];
                }
            } else if (c9 == 7) {
                if (aq == 0) {
#pragma unroll
                    for (int u = 0; u < 2; u++)
                        nt2[u] = (col[u] >= 0) ? node_type[col[u]] : -1;
                }
                int kb = t * TSTRIDE + 256;
                bnxt[0] = *(const bf16x8*)&btp0[kb];
                bnxt[1] = *(const bf16x8*)&btp1[kb];
                if (t < 6) {
                    coln[0] = (st_n + half     < en_n) ? elist[st_n + half]     : -1;
                    coln[1] = (st_n + half + 2 < en_n) ? elist[st_n + half + 2] : -1;
                }
            } else {  // c9 == 8: prefetch chunk 0 of next type
                if (t < 6) {
                    int cb = aq * 8;
#pragma unroll
                    for (int u = 0; u < 2; u++)
                        if (coln[u] >= 0) gv[u] = *(const u16x8*)&y[(size_t)coln[u] * 256 + cb];
                    int kb = (t + 1) * TSTRIDE;
                    bnxt[0] = *(const bf16x8*)&btp0[kb];
                    bnxt[1] = *(const bf16x8*)&btp1[kb];
                }
            }
            // ---- MFMA ----
            __builtin_amdgcn_s_setprio(1);
#pragma unroll
            for (int i = 0; i < 4; i++)
#pragma unroll
                for (int j = 0; j < 2; j++)
                    acc[i][j] = __builtin_amdgcn_mfma_f32_16x16x32_bf16(a[i], bcur[j], acc[i][j], 0, 0, 0);
            __builtin_amdgcn_s_setprio(0);
            // ---- fold prefetched data into a8 ----
            if (c9 < 7) {
#pragma unroll
                for (int u = 0; u < 2; u++)
                    if (col[u] >= 0) {
#pragma unroll
                        for (int j = 0; j < 8; j++) a8[j] += bf2f(gv[u][j]);
                    }
                if (en - st > 4) {
                    int cb = (c9 + 1) * 32 + aq * 8;
                    for (int e = st + 4 + half; e < en; e += 2) {
                        u16x8 v = *(const u16x8*)&y[(size_t)elist[e] * 256 + cb];
#pragma unroll
                        for (int j = 0; j < 8; j++) a8[j] += bf2f(v[j]);
                    }
                }
            } else if (c9 == 7) {
                if (aq == 0) {
#pragma unroll
                    for (int u = 0; u < 2; u++)
                        if (col[u] >= 0) {
#pragma unroll
                            for (int j = 0; j < 7; j++) a8[j] += (nt2[u] == j) ? 1.f : 0.f;
                        }
                    if (en - st > 4)
                        for (int e = st + 4 + half; e < en; e += 2) {
                            int nt = node_type[elist[e]];
#pragma unroll
                            for (int j = 0; j < 7; j++) a8[j] += (nt == j) ? 1.f : 0.f;
                        }
                }
            } else {  // c9 == 8
                if (t < 6) {
#pragma unroll
                    for (int u = 0; u < 2; u++)
                        if (coln[u] >= 0) {
#pragma unroll
                            for (int j = 0; j < 8; j++) a8[j] += bf2f(gv[u][j]);
                        }
                    if (en_n - st_n > 4)
                        for (int e = st_n + 4 + half; e < en_n; e += 2) {
                            u16x8 v = *(const u16x8*)&y[(size_t)elist[e] * 256 + aq * 8];
#pragma unroll
                            for (int j = 0; j < 8; j++) a8[j] += bf2f(v[j]);
                        }
                    col[0] = coln[0]; col[1] = coln[1];
                    st = st_n; en = en_n;
                }
            }
            bcur[0] = bnxt[0]; bcur[1] = bnxt[1];
            buf ^= 1;
        }
    }

    // ---- epilogue ----
#pragma unroll
    for (int i = 0; i < 4; i++) {
#pragma unroll
        for (int r = 0; r < 4; r++) {
            size_t m = (size_t)m0 + i * 16 + lq * 4 + r;
            float addv[2];
            if (mode == 0) {
                int b = batch_id[m];
#pragma unroll
                for (int j = 0; j < 2; j++) addv[j] = embout[b * 256 + wn * 32 + j * 16 + lm];
            } else {
#pragma unroll
                for (int j = 0; j < 2; j++) addv[j] = xres[m * 256 + wn * 32 + j * 16 + lm];
            }
#pragma unroll
            for (int j = 0; j < 2; j++) {
                int n = wn * 32 + j * 16 + lm;
                out[m * 256 + n] = acc[i][j][r] + addv[j];
            }
        }
    }
}

// ---------- host ----------
extern "C" void kernel_launch(void* const* d_in, const int* in_sizes, int n_in,
                              void* d_out, int out_size, void* d_ws, size_t ws_size,
                              hipStream_t stream) {
    // All float tensors are FLOAT32 (reference uses jnp.float32 throughout).
    const float* x    = (const float*)d_in[0];
    const float* emb  = (const float*)d_in[1];
    const int* bid    = (const int*)d_in[2];
    const int* ei     = (const int*)d_in[3];
    const int* et     = (const int*)d_in[4];
    const int* ntp    = (const int*)d_in[5];
    const float* gn1w = (const float*)d_in[6];
    const float* gn1b = (const float*)d_in[7];
    const float* w1   = (const float*)d_in[8];
    const float* embw = (const float*)d_in[9];
    const float* embb = (const float*)d_in[10];
    const float* gn2w = (const float*)d_in[11];
    const float* gn2b = (const float*)d_in[12];
    const float* w2   = (const float*)d_in[13];
    float* out = (float*)d_out;

    char* p = (char*)d_ws;
    size_t off = 0;
    auto nxt = [&](size_t bytes) -> void* {
        void* r = p + off;
        off += (bytes + 255) & ~(size_t)255;
        return r;
    };
    // ws budget ~43 MB
    u16*   y       = (u16*)nxt((size_t)N_NODES * 256 * 2);     // 33.5 MB (bf16 stage)
    u16*   Wt1     = (u16*)nxt((size_t)256 * GK * 2);          // 1.03 MB
    u16*   Wt2     = (u16*)nxt((size_t)256 * GK * 2);          // 1.03 MB
    float* embout  = (float*)nxt(8 * 256 * 4);
    float* S       = (float*)nxt(2048 * 4);
    float* Q       = (float*)nxt(2048 * 4);
    float* gmean   = (float*)nxt(256 * 4);
    float* gistd   = (float*)nxt(256 * 4);
    int*   cnt     = (int*)nxt(8 * 4);
    int*   offs    = (int*)nxt((size_t)NSEG * 4);              // hist, then offsets in place
    int*   cursor  = (int*)nxt((size_t)NSEG * 4);
    int*   parts   = (int*)nxt(1024 * 4);
    int*   elist   = (int*)nxt((size_t)E_EDGES * 4);
    float* h2      = out;   // d_out doubles as h2 (dead before final write)
    (void)ws_size; (void)in_sizes; (void)n_in; (void)out_size;

    // 1. zero hist + S/Q + cnt
    zero_kernel<<<1792, 256, 0, stream>>>(offs, S, Q, cnt);
    // 2. batch counts (reused by both finalize calls)
    count_kernel<<<256, 256, 0, stream>>>(bid, cnt);
    // 3. weight transpose/pad (f32->bf16, coalesced) + emb GEMM
    prep_kernel<<<1009, 256, 0, stream>>>(w1, w2, Wt1, Wt2, emb, embw, embb, embout);
    // 4-6. GN1 + SiLU -> y
    stats_kernel<<<1024, 256, 0, stream>>>(x, bid, S, Q);
    finalize_kernel<<<1, 256, 0, stream>>>(cnt, S, Q, gmean, gistd);
    norm_silu_kernel<<<8192, 256, 0, stream>>>(x, bid, gmean, gistd, gn1w, gn1b, y);
    // 7-11. CSR build (shared by both convs)
    hist_kernel<<<1792, 256, 0, stream>>>(ei, et, offs);
    scan1_kernel<<<896, 512, 0, stream>>>(offs, parts);
    scan2_kernel<<<1, 1024, 0, stream>>>(parts);
    scan3_kernel<<<896, 512, 0, stream>>>(offs, parts, cursor);
    fill_kernel<<<1792, 256, 0, stream>>>(ei, et, cursor, elist);
    // 12. conv1: fused aggregate+GEMM(+emb) -> h2 (in d_out)
    gemm_fused_kernel<<<1024, 512, 0, stream>>>(y, Wt1, offs, cursor, elist, ntp, bid, embout, x, h2, 0);
    // 13-15. GN2 + SiLU -> y   (finalize zeroed S/Q after GN1)
    stats_kernel<<<1024, 256, 0, stream>>>(h2, bid, S, Q);
    finalize_kernel<<<1, 256, 0, stream>>>(cnt, S, Q, gmean, gistd);
    norm_silu_kernel<<<8192, 256, 0, stream>>>(h2, bid, gmean, gistd, gn2w, gn2b, y);
    // 16. conv2: fused aggregate+GEMM(+x skip) -> out
    gemm_fused_kernel<<<1024, 512, 0, stream>>>(y, Wt2, offs, cursor, elist, ntp, bid, embout, x, out, 1);
}